// Round 11
// baseline (847.381 us; speedup 1.0000x reference)
//
#include <hip/hip_runtime.h>
#include <hip/hip_bf16.h>
#include <math.h>

#define B_      256
#define CHANS   22
#define SAMPLES 1125
#define DEPTH   9
#define CD1     24
#define CD2     9
#define KT      75
#define W1      1051
#define WP      210
#define FEAT    1890
#define TW      11
#define NT      96   // 96*11 = 1056 >= 1051

// workspace float offsets
#define WS_D     0      // 24    folded conv bias
#define WS_CC1   24     // 216   (legacy layout, unused by main now)
#define WS_B3    240    // 9 (+pad)
#define WS_B4    249    // 9
#define WS_BL    258    // 45    summed cheby bias per layer
#define WS_CC2   303    // 198   a4*cconv2_w [f][c]
#define WS_W2T   504    // 528   folded stage1 weight [c][o] (even base)
#define WS_KTB   1032   // f16[32][96] depthwise taps (1536 f)
#define WS_T16   2568   // f16[2 planes hi/lo*4096][2 Tsel][32][32] (2048 f)
#define WS_CC1T  4616   // 24*12 transposed cconv1 [i][o pad12] (288 f, even)
#define WS_WCB   4904   // 5*9*3*12 cheby W [l][f][k][o pad12] (1620 f, even)
#define WS_Z     6600   // 256*9*1051 z-buffer

#define LOSCALE    4096.0f
#define LOSCALE_I  2.44140625e-4f   // 1/4096, exact

typedef _Float16 half8 __attribute__((ext_vector_type(8)));
typedef float f32x4  __attribute__((ext_vector_type(4)));
typedef float v2f    __attribute__((ext_vector_type(2)));

__device__ __forceinline__ v2f V2s(float c) { return (v2f){c, c}; }

// branchless gelu: A&S 7.1.26 erf (|err|<=1.5e-7), scalar
__device__ __forceinline__ float gelu_fast(float v) {
    float u = v * 0.70710678118654752f;
    float s = fabsf(u);
    float t = __builtin_amdgcn_rcpf(fmaf(0.3275911f, s, 1.0f));
    float p = fmaf(fmaf(fmaf(fmaf(1.061405429f, t, -1.453152027f), t,
                             1.421413741f), t, -0.284496736f), t, 0.254829592f) * t;
    float e = __builtin_amdgcn_exp2f(s * s * -1.4426950408889634f);
    float er = copysignf(fmaf(-p, e, 1.0f), u);
    return fmaf(0.5f * v, er, 0.5f * v);
}

// 2-wide gelu: packed-f32 (v_pk_*) for the polynomial chain
__device__ __forceinline__ v2f gelu2(v2f v) {
    v2f u = v * 0.70710678118654752f;
    v2f s = __builtin_elementwise_abs(u);
    v2f den = __builtin_elementwise_fma(s, V2s(0.3275911f), V2s(1.0f));
    v2f t;
    t.x = __builtin_amdgcn_rcpf(den.x);
    t.y = __builtin_amdgcn_rcpf(den.y);
    v2f p = __builtin_elementwise_fma(t, V2s(1.061405429f), V2s(-1.453152027f));
    p = __builtin_elementwise_fma(p, t, V2s(1.421413741f));
    p = __builtin_elementwise_fma(p, t, V2s(-0.284496736f));
    p = __builtin_elementwise_fma(p, t, V2s(0.254829592f));
    p = p * t;
    v2f q = (s * s) * -1.4426950408889634f;
    v2f e;
    e.x = __builtin_amdgcn_exp2f(q.x);
    e.y = __builtin_amdgcn_exp2f(q.y);
    v2f er = __builtin_elementwise_copysign(
        __builtin_elementwise_fma(-p, e, V2s(1.0f)), u);
    v2f hv = v * 0.5f;
    return __builtin_elementwise_fma(hv, er, hv);
}

__device__ __forceinline__ half8 ld_half8(const _Float16* p) {
    union { uint2 u[2]; half8 h; } r;
    r.u[0] = *(const uint2*)p;
    r.u[1] = *(const uint2*)(p + 4);
    return r.h;
}

__global__ __launch_bounds__(256) void precompute_kernel(
    const float* __restrict__ cw, const float* __restrict__ t1w,
    const float* __restrict__ bn1, const float* __restrict__ t2w,
    const float* __restrict__ bn2, const float* __restrict__ cc1w,
    const float* __restrict__ bn3, const float* __restrict__ A,
    const float* __restrict__ Am, const float* __restrict__ cbW,
    const float* __restrict__ cbB, const float* __restrict__ cc2w,
    const float* __restrict__ bn4, float* __restrict__ ws)
{
    __shared__ float a1[CD1], a2[CD1];
    __shared__ float a3[CD2], a4[CD2];
    __shared__ float Ap[484], As[484], dis[22], L1s[484], L2s[484];
    const int tid = threadIdx.x;

    if (tid < CD1) {
        float g1 = bn1[tid], be1 = bn1[24 + tid], m1 = bn1[48 + tid], v1 = bn1[72 + tid];
        a1[tid] = g1 * rsqrtf(v1 + 1e-5f);
        float b1v = be1 - m1 * a1[tid];
        float g2 = bn2[tid], be2 = bn2[24 + tid], m2 = bn2[48 + tid], v2 = bn2[72 + tid];
        a2[tid] = g2 * rsqrtf(v2 + 1e-5f);
        float b2v = be2 - m2 * a2[tid];
        float S = 0.0f;
        for (int k = 0; k < KT; ++k) S += t2w[tid * KT + k];
        ws[WS_D + tid] = a2[tid] * b1v * S + b2v;
    }
    if (tid < CD2) {
        float g3 = bn3[tid], be3 = bn3[9 + tid], m3 = bn3[18 + tid], v3 = bn3[27 + tid];
        a3[tid] = g3 * rsqrtf(v3 + 1e-5f);
        ws[WS_B3 + tid] = be3 - m3 * a3[tid];
        float g4 = bn4[tid], be4 = bn4[9 + tid], m4 = bn4[18 + tid], v4 = bn4[27 + tid];
        a4[tid] = g4 * rsqrtf(v4 + 1e-5f);
        ws[WS_B4 + tid] = be4 - m4 * a4[tid];
    }
    __syncthreads();

    // W2T[c][o] = a2*a1*(t1w . cw)
    for (int e = tid; e < CHANS * 24; e += blockDim.x) {
        int c = e / 24, o = e - c * 24;
        float m = 0.0f;
        for (int h = 0; h < DEPTH; ++h) m += t1w[o * DEPTH + h] * cw[h * CHANS + c];
        ws[WS_W2T + e] = a2[o] * a1[o] * m;
    }
    // KTB f16 [32][96]: depthwise taps, rows o, cols k
    {
        _Float16* ktb = (_Float16*)(ws + WS_KTB);
        for (int e = tid; e < 32 * 96; e += blockDim.x) {
            int o = e / 96, k = e - o * 96;
            float v = (o < CD1 && k < KT) ? t2w[o * KT + k] : 0.0f;
            ktb[e] = (_Float16)v;
        }
    }
    for (int e = tid; e < CD2 * CD1; e += blockDim.x) {
        int o = e / CD1;
        ws[WS_CC1 + e] = a3[o] * cc1w[e] * 22.0f;
    }
    // CC1T [i][o pad12] for packed-pair loads in P4
    for (int e = tid; e < 288; e += blockDim.x) {
        int i = e / 12, o = e - i * 12;
        ws[WS_CC1T + e] = (o < 9) ? a3[o] * cc1w[o * CD1 + i] * 22.0f : 0.0f;
    }
    // WCB [l][f][k][o pad12] for packed-pair loads in P5 contraction
    for (int e = tid; e < 1620; e += blockDim.x) {
        int l = e / 324, r = e - l * 324;
        int f = r / 36, r2 = r - f * 36;
        int k = r2 / 12, o = r2 - k * 12;
        ws[WS_WCB + e] = (o < 9) ? cbW[((l * 3 + k) * 9 + f) * 9 + o] : 0.0f;
    }
    for (int e = tid; e < CD2 * CHANS; e += blockDim.x) {
        int f = e / CHANS;
        ws[WS_CC2 + e] = a4[f] * cc2w[e];
    }
    for (int e = tid; e < 45; e += blockDim.x) {
        int l = e / 9, o = e - l * 9;
        ws[WS_BL + e] = cbB[(l * 3 + 0) * 9 + o] + cbB[(l * 3 + 1) * 9 + o] + cbB[(l * 3 + 2) * 9 + o];
    }
    for (int e = tid; e < 484; e += blockDim.x) {
        int c = e / 22, d = e - c * 22;
        float v = A[e] / (1.0f + expf(-Am[e]));
        v = fmaxf(v, 0.0f);
        if (c == d) v = 0.0f;
        Ap[e] = v;
    }
    __syncthreads();
    for (int e = tid; e < 484; e += blockDim.x) {
        int c = e / 22, d = e - c * 22;
        As[e] = Ap[e] + Ap[d * 22 + c];
    }
    __syncthreads();
    if (tid < 22) {
        float s = 0.0f;
        for (int d = 0; d < 22; ++d) s += As[tid * 22 + d];
        dis[tid] = rsqrtf(s + 1e-10f);
    }
    __syncthreads();
    for (int e = tid; e < 484; e += blockDim.x) {
        int c = e / 22, d = e - c * 22;
        L1s[e] = -dis[c] * As[e] * dis[d];   // 2L/lmax - I, lmax=2
    }
    __syncthreads();
    for (int e = tid; e < 484; e += blockDim.x) {
        int c = e / 22, d = e - c * 22;
        float s = 0.0f;
        for (int k2 = 0; k2 < 22; ++k2) s += L1s[c * 22 + k2] * L1s[k2 * 22 + d];
        L2s[e] = 2.0f * s - (c == d ? 1.0f : 0.0f);
    }
    __syncthreads();
    // T16: plane0 = hi f16; plane1 = (v - hi) * 4096 (keeps lo in f16 normal range)
    {
        _Float16* t16 = (_Float16*)(ws + WS_T16);
        for (int e = tid; e < 4096; e += blockDim.x) {
            int plane = e >> 11, rem = e & 2047;
            int which = rem >> 10, r = (rem >> 5) & 31, d = rem & 31;
            float v = 0.0f;
            if (r < 22 && d < 22) v = which ? L2s[r * 22 + d] : L1s[r * 22 + d];
            _Float16 hi = (_Float16)v;
            t16[e] = plane ? (_Float16)((v - (float)hi) * LOSCALE) : hi;
        }
    }
}

// ---- LDS layout (5 blocks/CU) ----
// halves: XA hi [0,3564), XA lo [3564,7128)  ([99 rows ft][36 d] each;
//         P1 x-window 4928 halves overlays [0,4928) — dead after P2)
//         OG [7128,12980)  ([11 t][532])
// floats: YF [3564,7920) = [2 k][9 f][242 ct]  (born P5; OG dead by then)
//         OSF 24x12 @6496, XPF 24x11 @6784 (die after P4; inside future YF)
#define XA16H 0
#define XA16L 3564
#define OG16  7128
#define YF    3564      // float index
#define OSF   6496     // float index
#define XPF   6784     // float index
#define SMEM_F 7920    // 31680 B -> 5 blocks/CU

__global__ __launch_bounds__(256, 5) void main_kernel(
    const float* __restrict__ x, const float* __restrict__ daw_g,
    const float* __restrict__ dab_g, float* __restrict__ ws)
{
    __shared__ float sm[SMEM_F];
    _Float16* sm16 = (_Float16*)sm;
    const int tid = threadIdx.x;
    const int b = blockIdx.y;
    const int w0 = blockIdx.x * TW;
    const float* cst = ws;
    float* zbuf = ws + WS_Z;

    const int lane = tid & 63;
    const int wid  = tid >> 6;
    const int quad = lane >> 4;
    const int lt   = lane & 15;

    // Phase 1: stage x window f16, copies at even and +1 shift (halves [0,4928))
    for (int e = tid; e < 22 * 112; e += 256) {
        int ch = e / 112, j = e - ch * 112;
        int s = w0 + j;
        float v = (j < 85 && s < SAMPLES) ? x[(b * CHANS + ch) * SAMPLES + s] : 0.0f;
        _Float16 h = (_Float16)v;
        sm16[e] = h;
        if (j > 0) sm16[2464 + e - 1] = h;
        if (j == 111) sm16[2464 + e] = (_Float16)0.0f;
    }
    __syncthreads();

    // Phase 2: depthwise conv as MFMA-f16 GEMM per channel
    {
        half8 afr0[3], afr1[3];
        const _Float16* ktb = (const _Float16*)(cst + WS_KTB);
        #pragma unroll
        for (int kt = 0; kt < 3; ++kt) {
            afr0[kt] = *(const half8*)(ktb + lt * 96 + kt * 32 + quad * 8);
            afr1[kt] = *(const half8*)(ktb + (lt + 16) * 96 + kt * 32 + quad * 8);
        }
        const int xebase = (lt & 1) ? (2464 - 1 + lt) : lt;  // parity-selected copy
        const int* smi = (const int*)sm;

        for (int c = wid; c < CHANS; c += 4) {
            f32x4 acc0 = {0.f, 0.f, 0.f, 0.f}, acc1 = {0.f, 0.f, 0.f, 0.f};
            #pragma unroll
            for (int kt = 0; kt < 3; ++kt) {
                int bi = (xebase + c * 112 + quad * 8 + kt * 32) >> 1;
                union { int i[4]; half8 s; } B;
                B.i[0] = smi[bi];     B.i[1] = smi[bi + 1];
                B.i[2] = smi[bi + 2]; B.i[3] = smi[bi + 3];
                acc0 = __builtin_amdgcn_mfma_f32_16x16x32_f16(afr0[kt], B.s, acc0, 0, 0, 0);
                acc1 = __builtin_amdgcn_mfma_f32_16x16x32_f16(afr1[kt], B.s, acc1, 0, 0, 0);
            }
            const int t = lt;
            if (t < TW) {
                {
                    const v2f* w2v = (const v2f*)(cst + WS_W2T + c * 24 + quad * 4);
                    const v2f* ddv = (const v2f*)(cst + WS_D + quad * 4);
                    v2f g01 = gelu2(__builtin_elementwise_fma(w2v[0], (v2f){acc0[0], acc0[1]}, ddv[0]));
                    v2f g23 = gelu2(__builtin_elementwise_fma(w2v[1], (v2f){acc0[2], acc0[3]}, ddv[1]));
                    union { _Float16 h[4]; uint2 v; } pk;
                    pk.h[0] = (_Float16)g01.x; pk.h[1] = (_Float16)g01.y;
                    pk.h[2] = (_Float16)g23.x; pk.h[3] = (_Float16)g23.y;
                    *(uint2*)&sm16[OG16 + t * 532 + c * 24 + quad * 4] = pk.v;
                }
                if (quad < 2) {
                    const v2f* w2v = (const v2f*)(cst + WS_W2T + c * 24 + 16 + quad * 4);
                    const v2f* ddv = (const v2f*)(cst + WS_D + 16 + quad * 4);
                    v2f g01 = gelu2(__builtin_elementwise_fma(w2v[0], (v2f){acc1[0], acc1[1]}, ddv[0]));
                    v2f g23 = gelu2(__builtin_elementwise_fma(w2v[1], (v2f){acc1[2], acc1[3]}, ddv[1]));
                    union { _Float16 h[4]; uint2 v; } pk;
                    pk.h[0] = (_Float16)g01.x; pk.h[1] = (_Float16)g01.y;
                    pk.h[2] = (_Float16)g23.x; pk.h[3] = (_Float16)g23.y;
                    *(uint2*)&sm16[OG16 + t * 532 + c * 24 + 16 + quad * 4] = pk.v;
                }
            }
        }
    }
    __syncthreads();

    // Phase 3: depth attention: mean over c, (7,1) depth conv, softmax over depth
    for (int e = tid; e < CD1 * TW; e += 256) {
        int d = e / TW, tt = e - d * TW;
        float s = 0.0f;
        #pragma unroll
        for (int ch = 0; ch < CHANS; ++ch) s += (float)sm16[OG16 + tt * 532 + ch * 24 + d];
        sm[XPF + e] = s * (1.0f / 22.0f);
    }
    __syncthreads();
    for (int e = tid; e < CD1 * TW; e += 256) {
        int d = e / TW, tt = e - d * TW;
        float y = dab_g[0];
        #pragma unroll
        for (int j = 0; j < 7; ++j) {
            int dd = d + j - 3;
            if (dd >= 0 && dd < CD1) y += daw_g[j] * sm[XPF + dd * TW + tt];
        }
        sm[OSF + d * 12 + tt] = y;
    }
    __syncthreads();
    if (tid < TW) {
        float mx = -1e30f;
        for (int d = 0; d < CD1; ++d) mx = fmaxf(mx, sm[OSF + d * 12 + tid]);
        float sum = 0.0f;
        for (int d = 0; d < CD1; ++d) {
            float e2 = expf(sm[OSF + d * 12 + tid] - mx);
            sm[OSF + d * 12 + tid] = e2;
            sum += e2;
        }
        float inv = 1.0f / sum;
        for (int d = 0; d < CD1; ++d) sm[OSF + d * 12 + tid] *= inv;
    }
    __syncthreads();

    const int c4 = tid / TW;        // 0..21 (tid<242)
    const int t4 = tid - c4 * TW;   // 0..10
    const bool act = (tid < 242);

    // Zero XA pad cols 22..31 for rows 0..98 (kills stale-LDS in the A*0 path)
    for (int e = tid; e < 990; e += 256) {
        int row = e / 10, d = 22 + (e - row * 10);
        sm16[XA16H + row * 36 + d] = (_Float16)0.0f;
        sm16[XA16L + row * 36 + d] = (_Float16)0.0f;
    }

    // Phase 4: cconv1 (packed-f32 pairs) -> xo registers; write XA hi + lo*4096
    float xo[CD2];
    if (act) {
        float garr[CD1];
        {
            union { uint u[12]; _Float16 h[24]; } gg;
            const uint* gsrc = (const uint*)&sm16[OG16 + t4 * 532 + c4 * 24];
            #pragma unroll
            for (int q = 0; q < 12; ++q) gg.u[q] = gsrc[q];
            #pragma unroll
            for (int i = 0; i < 24; ++i) garr[i] = (float)gg.h[i];
        }
        v2f acc2[4];
        acc2[0] = *(const v2f*)(cst + WS_B3 + 0);
        acc2[1] = *(const v2f*)(cst + WS_B3 + 2);
        acc2[2] = *(const v2f*)(cst + WS_B3 + 4);
        acc2[3] = *(const v2f*)(cst + WS_B3 + 6);
        float acc8 = cst[WS_B3 + 8];
        #pragma unroll
        for (int i = 0; i < CD1; ++i) {
            float s = sm[OSF + i * 12 + t4];
            float p = s * garr[i];
            v2f pv = V2s(p);
            const v2f* wv = (const v2f*)(cst + WS_CC1T + i * 12);
            acc2[0] = __builtin_elementwise_fma(wv[0], pv, acc2[0]);
            acc2[1] = __builtin_elementwise_fma(wv[1], pv, acc2[1]);
            acc2[2] = __builtin_elementwise_fma(wv[2], pv, acc2[2]);
            acc2[3] = __builtin_elementwise_fma(wv[3], pv, acc2[3]);
            acc8 = fmaf(cst[WS_CC1T + i * 12 + 8], p, acc8);
        }
        xo[0] = acc2[0].x; xo[1] = acc2[0].y; xo[2] = acc2[1].x; xo[3] = acc2[1].y;
        xo[4] = acc2[2].x; xo[5] = acc2[2].y; xo[6] = acc2[3].x; xo[7] = acc2[3].y;
        xo[8] = acc8;
        #pragma unroll
        for (int f = 0; f < 9; ++f) {
            float v = xo[f];
            _Float16 hi = (_Float16)v;
            _Float16 lo = (_Float16)((v - (float)hi) * LOSCALE);
            int row = (t4 * 9 + f) * 36 + c4;
            sm16[XA16H + row] = hi;
            sm16[XA16L + row] = lo;
        }
    }
    __syncthreads();

    // Phase 5: 5 Chebyshev layers. GEMM-1 via scaled split-f16 MFMA (f32-grade);
    // contraction (27->9) in packed-f32 VALU with register xo.
    const int Tsel = wid >> 1;
    const int ccG1 = (wid & 1) * 16 + lt;
    const _Float16* t16 = (const _Float16*)(cst + WS_T16);
    const half8 bT_hi = *(const half8*)(t16 + Tsel * 1024 + ccG1 * 32 + quad * 8);
    const half8 bT_lo = *(const half8*)(t16 + 2048 + Tsel * 1024 + ccG1 * 32 + quad * 8);
    const f32x4 zz = {0.f, 0.f, 0.f, 0.f};
    const f32x4 scv = {LOSCALE_I, LOSCALE_I, LOSCALE_I, LOSCALE_I};

    #pragma unroll 1
    for (int l = 0; l < 5; ++l) {
        // GEMM-1: Y = X * T^T; 6 full M-tiles + 1 overlapping tail tile (rows 83..98)
        f32x4 y[7];
        #pragma unroll
        for (int mt = 0; mt < 7; ++mt) {
            const int rowb = (mt < 6) ? mt * 16 : 83;
            half8 ah = ld_half8(&sm16[XA16H + (rowb + lt) * 36 + quad * 8]);
            half8 al = ld_half8(&sm16[XA16L + (rowb + lt) * 36 + quad * 8]);
            f32x4 ahi = __builtin_amdgcn_mfma_f32_16x16x32_f16(ah, bT_hi, zz, 0, 0, 0);
            f32x4 alo = __builtin_amdgcn_mfma_f32_16x16x32_f16(al, bT_hi, zz, 0, 0, 0);
            alo = __builtin_amdgcn_mfma_f32_16x16x32_f16(ah, bT_lo, alo, 0, 0, 0);
            y[mt] = __builtin_elementwise_fma(alo, scv, ahi);
        }
        // scatter Y f32 -> YF[Tsel][f][c*11+t]
        if (ccG1 < 22) {
            const int cb = ccG1 * 11;
            #pragma unroll
            for (int mt = 0; mt < 6; ++mt) {
                int m0 = mt * 16 + quad * 4;       // <= 92: always in range
                int t0 = (m0 * 57) >> 9;
                int f0 = m0 - 9 * t0;
                #pragma unroll
                for (int r = 0; r < 4; ++r) {
                    sm[YF + (Tsel * 9 + f0) * 242 + cb + t0] = y[mt][r];
                    ++f0; if (f0 == 9) { f0 = 0; ++t0; }
                }
            }
            {   // tail tile: m = 83 + quad*4 + r; keep only m=96..98 (t=10, f=6..8)
                int m0 = 83 + quad * 4;
                #pragma unroll
                for (int r = 0; r < 4; ++r) {
                    int m = m0 + r;
                    if (m >= 96)
                        sm[YF + (Tsel * 9 + (m - 90)) * 242 + cb + 10] = y[6][r];
                }
            }
        }
        __syncthreads();

        if (act) {
            const float* blp = cst + WS_BL + l * 9;
            v2f o2_0 = {blp[0], blp[1]}, o2_1 = {blp[2], blp[3]};
            v2f o2_2 = {blp[4], blp[5]}, o2_3 = {blp[6], blp[7]};
            float o8 = blp[8];
            #pragma unroll
            for (int f = 0; f < CD2; ++f) {
                float xv  = xo[f];
                float yv1 = sm[YF + f * 242 + tid];
                float yv2 = sm[YF + (9 + f) * 242 + tid];
                v2f xp = V2s(xv), y1p = V2s(yv1), y2p = V2s(yv2);
                const float* wb = cst + WS_WCB + (l * 9 + f) * 36;
                const v2f* w0 = (const v2f*)(wb);
                const v2f* w1 = (const v2f*)(wb + 12);
                const v2f* w2 = (const v2f*)(wb + 24);
                o2_0 = __builtin_elementwise_fma(w0[0], xp,
                        __builtin_elementwise_fma(w1[0], y1p,
                         __builtin_elementwise_fma(w2[0], y2p, o2_0)));
                o2_1 = __builtin_elementwise_fma(w0[1], xp,
                        __builtin_elementwise_fma(w1[1], y1p,
                         __builtin_elementwise_fma(w2[1], y2p, o2_1)));
                o2_2 = __builtin_elementwise_fma(w0[2], xp,
                        __builtin_elementwise_fma(w1[2], y1p,
                         __builtin_elementwise_fma(w2[2], y2p, o2_2)));
                o2_3 = __builtin_elementwise_fma(w0[3], xp,
                        __builtin_elementwise_fma(w1[3], y1p,
                         __builtin_elementwise_fma(w2[3], y2p, o2_3)));
                o8 = fmaf(wb[8], xv, fmaf(wb[20], yv1, fmaf(wb[32], yv2, o8)));
            }
            o2_0 = __builtin_elementwise_max(o2_0, V2s(0.0f));
            o2_1 = __builtin_elementwise_max(o2_1, V2s(0.0f));
            o2_2 = __builtin_elementwise_max(o2_2, V2s(0.0f));
            o2_3 = __builtin_elementwise_max(o2_3, V2s(0.0f));
            xo[0] = o2_0.x; xo[1] = o2_0.y; xo[2] = o2_1.x; xo[3] = o2_1.y;
            xo[4] = o2_2.x; xo[5] = o2_2.y; xo[6] = o2_3.x; xo[7] = o2_3.y;
            xo[8] = fmaxf(o8, 0.0f);
            if (l < 4) {
                #pragma unroll
                for (int f = 0; f < 9; ++f) {
                    float v = xo[f];
                    _Float16 hi = (_Float16)v;
                    _Float16 lo = (_Float16)((v - (float)hi) * LOSCALE);
                    int row = (t4 * 9 + f) * 36 + c4;
                    sm16[XA16H + row] = hi;
                    sm16[XA16L + row] = lo;
                }
            }
        }
        __syncthreads();
    }

    // final X f32 -> XF (reuse YF region; all YF reads completed at last barrier)
    if (act) {
        #pragma unroll
        for (int f = 0; f < 9; ++f) sm[YF + f * 242 + tid] = xo[f];
    }
    __syncthreads();

    // Phase 6: depthwise channel conv (folded bn4) + gelu -> zbuf
    if (tid < CD2 * TW) {
        int f = tid / TW, tt = tid - f * TW;
        float a = cst[WS_B4 + f];
        #pragma unroll
        for (int ch = 0; ch < CHANS; ++ch)
            a = fmaf(cst[WS_CC2 + f * CHANS + ch], sm[YF + f * 242 + ch * 11 + tt], a);
        float z = gelu_fast(a);
        int w = w0 + tt;
        if (w < W1) zbuf[(b * CD2 + f) * W1 + w] = z;
    }
}

__global__ __launch_bounds__(256) void head_kernel(
    const float* __restrict__ ws, const float* __restrict__ fc1w,
    const float* __restrict__ fc1b, const float* __restrict__ w1,
    const float* __restrict__ b1, const float* __restrict__ w2,
    const float* __restrict__ b2, float* __restrict__ out)
{
    __shared__ float red[5][256];
    __shared__ float l5[5];
    __shared__ float hbuf[64];
    const int tid = threadIdx.x;
    const int b = blockIdx.x;
    const float* zb = ws + WS_Z + b * CD2 * W1;

    float part[5] = {0, 0, 0, 0, 0};
    for (int i = tid; i < FEAT; i += 256) {
        int f = i / WP, t = i - f * WP;
        const float* zp = zb + f * W1 + 5 * t;
        float pooled = 0.2f * (zp[0] + zp[1] + zp[2] + zp[3] + zp[4]);
        #pragma unroll
        for (int j = 0; j < 5; ++j) part[j] = fmaf(pooled, fc1w[i * 5 + j], part[j]);
    }
    #pragma unroll
    for (int j = 0; j < 5; ++j) red[j][tid] = part[j];
    __syncthreads();
    for (int ofs = 128; ofs > 0; ofs >>= 1) {
        if (tid < ofs) {
            #pragma unroll
            for (int j = 0; j < 5; ++j) red[j][tid] += red[j][tid + ofs];
        }
        __syncthreads();
    }
    if (tid < 5) l5[tid] = red[tid][0] + fc1b[tid];
    __syncthreads();
    if (tid < 64) {
        float a = b1[tid];
        #pragma unroll
        for (int j = 0; j < 5; ++j) a = fmaf(l5[j], w1[j * 64 + tid], a);
        hbuf[tid] = (a > 0.0f) ? a : expm1f(a);
    }
    __syncthreads();
    if (tid == 0) {
        float o4[4];
        #pragma unroll
        for (int m = 0; m < 4; ++m) {
            float a = b2[m];
            for (int k = 0; k < 64; ++k) a = fmaf(hbuf[k], w2[k * 4 + m], a);
            o4[m] = a;
        }
        float mx = fmaxf(fmaxf(o4[0], o4[1]), fmaxf(o4[2], o4[3]));
        float s = 0.0f;
        #pragma unroll
        for (int m = 0; m < 4; ++m) { o4[m] = expf(o4[m] - mx); s += o4[m]; }
        float inv = 1.0f / s;
        #pragma unroll
        for (int m = 0; m < 4; ++m) out[b * 4 + m] = o4[m] * inv;
    }
}

extern "C" void kernel_launch(void* const* d_in, const int* in_sizes, int n_in,
                              void* d_out, int out_size, void* d_ws, size_t ws_size,
                              hipStream_t stream)
{
    const float* x    = (const float*)d_in[0];
    const float* cw   = (const float*)d_in[1];
    const float* t1w  = (const float*)d_in[2];
    const float* bn1  = (const float*)d_in[3];
    const float* t2w  = (const float*)d_in[4];
    const float* bn2  = (const float*)d_in[5];
    const float* daw  = (const float*)d_in[6];
    const float* dab  = (const float*)d_in[7];
    const float* cc1w = (const float*)d_in[8];
    const float* bn3  = (const float*)d_in[9];
    const float* A    = (const float*)d_in[10];
    const float* Am   = (const float*)d_in[11];
    const float* cbW  = (const float*)d_in[12];
    const float* cbB  = (const float*)d_in[13];
    const float* cc2w = (const float*)d_in[14];
    const float* bn4  = (const float*)d_in[15];
    const float* fc1w = (const float*)d_in[16];
    const float* fc1b = (const float*)d_in[17];
    const float* w1   = (const float*)d_in[18];
    const float* b1   = (const float*)d_in[19];
    const float* w2   = (const float*)d_in[20];
    const float* b2   = (const float*)d_in[21];
    float* ws  = (float*)d_ws;
    float* out = (float*)d_out;

    hipLaunchKernelGGL(precompute_kernel, dim3(1), dim3(256), 0, stream,
                       cw, t1w, bn1, t2w, bn2, cc1w, bn3, A, Am, cbW, cbB, cc2w, bn4, ws);
    hipLaunchKernelGGL(main_kernel, dim3(NT, B_), dim3(256), 0, stream,
                       x, daw, dab, ws);
    hipLaunchKernelGGL(head_kernel, dim3(B_), dim3(256), 0, stream,
                       ws, fc1w, fc1b, w1, b1, w2, b2, out);
}

// Round 12
// 801.471 us; speedup vs baseline: 1.0573x; 1.0573x over previous
//
#include <hip/hip_runtime.h>
#include <hip/hip_bf16.h>
#include <math.h>

#define B_      256
#define CHANS   22
#define SAMPLES 1125
#define DEPTH   9
#define CD1     24
#define CD2     9
#define KT      75
#define W1      1051
#define WP      210
#define FEAT    1890
#define TW      11
#define NT      96   // 96*11 = 1056 >= 1051

// workspace float offsets
#define WS_D     0      // 24    folded conv bias
#define WS_CC1   24     // 216   (legacy layout, unused by main now)
#define WS_B3    240    // 9 (+pad)
#define WS_B4    249    // 9
#define WS_BL    258    // 45    summed cheby bias per layer
#define WS_CC2   303    // 198   a4*cconv2_w [f][c]
#define WS_W2T   504    // 528   folded stage1 weight [c][o] (even base)
#define WS_KTB   1032   // f16[32][96] depthwise taps (1536 f)
#define WS_T16   2568   // f16[2 planes hi/lo*4096][2 Tsel][32][32] (2048 f)
#define WS_CC1T  4616   // 24*12 transposed cconv1 [i][o pad12] (288 f, even)
#define WS_WCB   4904   // 5*9*3*12 cheby W [l][f][k][o pad12] (1620 f, even)
#define WS_Z     6600   // 256*9*1051 z-buffer

#define LOSCALE    4096.0f
#define LOSCALE_I  2.44140625e-4f   // 1/4096, exact

typedef _Float16 half8 __attribute__((ext_vector_type(8)));
typedef float f32x4  __attribute__((ext_vector_type(4)));
typedef float v2f    __attribute__((ext_vector_type(2)));

__device__ __forceinline__ v2f V2s(float c) { return (v2f){c, c}; }

// branchless gelu: A&S 7.1.26 erf (|err|<=1.5e-7), scalar
__device__ __forceinline__ float gelu_fast(float v) {
    float u = v * 0.70710678118654752f;
    float s = fabsf(u);
    float t = __builtin_amdgcn_rcpf(fmaf(0.3275911f, s, 1.0f));
    float p = fmaf(fmaf(fmaf(fmaf(1.061405429f, t, -1.453152027f), t,
                             1.421413741f), t, -0.284496736f), t, 0.254829592f) * t;
    float e = __builtin_amdgcn_exp2f(s * s * -1.4426950408889634f);
    float er = copysignf(fmaf(-p, e, 1.0f), u);
    return fmaf(0.5f * v, er, 0.5f * v);
}

// 2-wide gelu: packed-f32 (v_pk_*) for the polynomial chain
__device__ __forceinline__ v2f gelu2(v2f v) {
    v2f u = v * 0.70710678118654752f;
    v2f s = __builtin_elementwise_abs(u);
    v2f den = __builtin_elementwise_fma(s, V2s(0.3275911f), V2s(1.0f));
    v2f t;
    t.x = __builtin_amdgcn_rcpf(den.x);
    t.y = __builtin_amdgcn_rcpf(den.y);
    v2f p = __builtin_elementwise_fma(t, V2s(1.061405429f), V2s(-1.453152027f));
    p = __builtin_elementwise_fma(p, t, V2s(1.421413741f));
    p = __builtin_elementwise_fma(p, t, V2s(-0.284496736f));
    p = __builtin_elementwise_fma(p, t, V2s(0.254829592f));
    p = p * t;
    v2f q = (s * s) * -1.4426950408889634f;
    v2f e;
    e.x = __builtin_amdgcn_exp2f(q.x);
    e.y = __builtin_amdgcn_exp2f(q.y);
    v2f er = __builtin_elementwise_copysign(
        __builtin_elementwise_fma(-p, e, V2s(1.0f)), u);
    v2f hv = v * 0.5f;
    return __builtin_elementwise_fma(hv, er, hv);
}

__device__ __forceinline__ half8 ld_half8(const _Float16* p) {
    union { uint2 u[2]; half8 h; } r;
    r.u[0] = *(const uint2*)p;
    r.u[1] = *(const uint2*)(p + 4);
    return r.h;
}

__global__ __launch_bounds__(256) void precompute_kernel(
    const float* __restrict__ cw, const float* __restrict__ t1w,
    const float* __restrict__ bn1, const float* __restrict__ t2w,
    const float* __restrict__ bn2, const float* __restrict__ cc1w,
    const float* __restrict__ bn3, const float* __restrict__ A,
    const float* __restrict__ Am, const float* __restrict__ cbW,
    const float* __restrict__ cbB, const float* __restrict__ cc2w,
    const float* __restrict__ bn4, float* __restrict__ ws)
{
    __shared__ float a1[CD1], a2[CD1];
    __shared__ float a3[CD2], a4[CD2];
    __shared__ float Ap[484], As[484], dis[22], L1s[484], L2s[484];
    const int tid = threadIdx.x;

    if (tid < CD1) {
        float g1 = bn1[tid], be1 = bn1[24 + tid], m1 = bn1[48 + tid], v1 = bn1[72 + tid];
        a1[tid] = g1 * rsqrtf(v1 + 1e-5f);
        float b1v = be1 - m1 * a1[tid];
        float g2 = bn2[tid], be2 = bn2[24 + tid], m2 = bn2[48 + tid], v2 = bn2[72 + tid];
        a2[tid] = g2 * rsqrtf(v2 + 1e-5f);
        float b2v = be2 - m2 * a2[tid];
        float S = 0.0f;
        for (int k = 0; k < KT; ++k) S += t2w[tid * KT + k];
        ws[WS_D + tid] = a2[tid] * b1v * S + b2v;
    }
    if (tid < CD2) {
        float g3 = bn3[tid], be3 = bn3[9 + tid], m3 = bn3[18 + tid], v3 = bn3[27 + tid];
        a3[tid] = g3 * rsqrtf(v3 + 1e-5f);
        ws[WS_B3 + tid] = be3 - m3 * a3[tid];
        float g4 = bn4[tid], be4 = bn4[9 + tid], m4 = bn4[18 + tid], v4 = bn4[27 + tid];
        a4[tid] = g4 * rsqrtf(v4 + 1e-5f);
        ws[WS_B4 + tid] = be4 - m4 * a4[tid];
    }
    __syncthreads();

    // W2T[c][o] = a2*a1*(t1w . cw)
    for (int e = tid; e < CHANS * 24; e += blockDim.x) {
        int c = e / 24, o = e - c * 24;
        float m = 0.0f;
        for (int h = 0; h < DEPTH; ++h) m += t1w[o * DEPTH + h] * cw[h * CHANS + c];
        ws[WS_W2T + e] = a2[o] * a1[o] * m;
    }
    // KTB f16 [32][96]: depthwise taps, rows o, cols k
    {
        _Float16* ktb = (_Float16*)(ws + WS_KTB);
        for (int e = tid; e < 32 * 96; e += blockDim.x) {
            int o = e / 96, k = e - o * 96;
            float v = (o < CD1 && k < KT) ? t2w[o * KT + k] : 0.0f;
            ktb[e] = (_Float16)v;
        }
    }
    for (int e = tid; e < CD2 * CD1; e += blockDim.x) {
        int o = e / CD1;
        ws[WS_CC1 + e] = a3[o] * cc1w[e] * 22.0f;
    }
    // CC1T [i][o pad12] for packed-pair loads in P4
    for (int e = tid; e < 288; e += blockDim.x) {
        int i = e / 12, o = e - i * 12;
        ws[WS_CC1T + e] = (o < 9) ? a3[o] * cc1w[o * CD1 + i] * 22.0f : 0.0f;
    }
    // WCB [l][f][k][o pad12] for packed-pair loads in P5 contraction
    for (int e = tid; e < 1620; e += blockDim.x) {
        int l = e / 324, r = e - l * 324;
        int f = r / 36, r2 = r - f * 36;
        int k = r2 / 12, o = r2 - k * 12;
        ws[WS_WCB + e] = (o < 9) ? cbW[((l * 3 + k) * 9 + f) * 9 + o] : 0.0f;
    }
    for (int e = tid; e < CD2 * CHANS; e += blockDim.x) {
        int f = e / CHANS;
        ws[WS_CC2 + e] = a4[f] * cc2w[e];
    }
    for (int e = tid; e < 45; e += blockDim.x) {
        int l = e / 9, o = e - l * 9;
        ws[WS_BL + e] = cbB[(l * 3 + 0) * 9 + o] + cbB[(l * 3 + 1) * 9 + o] + cbB[(l * 3 + 2) * 9 + o];
    }
    for (int e = tid; e < 484; e += blockDim.x) {
        int c = e / 22, d = e - c * 22;
        float v = A[e] / (1.0f + expf(-Am[e]));
        v = fmaxf(v, 0.0f);
        if (c == d) v = 0.0f;
        Ap[e] = v;
    }
    __syncthreads();
    for (int e = tid; e < 484; e += blockDim.x) {
        int c = e / 22, d = e - c * 22;
        As[e] = Ap[e] + Ap[d * 22 + c];
    }
    __syncthreads();
    if (tid < 22) {
        float s = 0.0f;
        for (int d = 0; d < 22; ++d) s += As[tid * 22 + d];
        dis[tid] = rsqrtf(s + 1e-10f);
    }
    __syncthreads();
    for (int e = tid; e < 484; e += blockDim.x) {
        int c = e / 22, d = e - c * 22;
        L1s[e] = -dis[c] * As[e] * dis[d];   // 2L/lmax - I, lmax=2
    }
    __syncthreads();
    for (int e = tid; e < 484; e += blockDim.x) {
        int c = e / 22, d = e - c * 22;
        float s = 0.0f;
        for (int k2 = 0; k2 < 22; ++k2) s += L1s[c * 22 + k2] * L1s[k2 * 22 + d];
        L2s[e] = 2.0f * s - (c == d ? 1.0f : 0.0f);
    }
    __syncthreads();
    // T16: plane0 = hi f16; plane1 = (v - hi) * 4096 (keeps lo in f16 normal range)
    {
        _Float16* t16 = (_Float16*)(ws + WS_T16);
        for (int e = tid; e < 4096; e += blockDim.x) {
            int plane = e >> 11, rem = e & 2047;
            int which = rem >> 10, r = (rem >> 5) & 31, d = rem & 31;
            float v = 0.0f;
            if (r < 22 && d < 22) v = which ? L2s[r * 22 + d] : L1s[r * 22 + d];
            _Float16 hi = (_Float16)v;
            t16[e] = plane ? (_Float16)((v - (float)hi) * LOSCALE) : hi;
        }
    }
}

// ---- LDS layout (5 blocks/CU via LDS; allocator budget left at 4 waves/EU
//      so no spills — occupancy is set by resources, not the declaration) ----
// halves: XA hi [0,3564), XA lo [3564,7128)  ([99 rows ft][36 d] each;
//         P1 x-window 4928 halves overlays [0,4928) — dead after P2)
//         OG [7128,12980)  ([11 t][532])
// floats: YF [3564,7920) = [2 k][9 f][242 ct]  (born P5; OG dead by then)
//         OSF 24x12 @6496, XPF 24x11 @6784 (die after P4; inside future YF)
#define XA16H 0
#define XA16L 3564
#define OG16  7128
#define YF    3564      // float index
#define OSF   6496     // float index
#define XPF   6784     // float index
#define SMEM_F 7920    // 31680 B -> 5 blocks/CU

__global__ __launch_bounds__(256, 4) void main_kernel(
    const float* __restrict__ x, const float* __restrict__ daw_g,
    const float* __restrict__ dab_g, float* __restrict__ ws)
{
    __shared__ float sm[SMEM_F];
    _Float16* sm16 = (_Float16*)sm;
    const int tid = threadIdx.x;
    const int b = blockIdx.y;
    const int w0 = blockIdx.x * TW;
    const float* cst = ws;
    float* zbuf = ws + WS_Z;

    const int lane = tid & 63;
    const int wid  = tid >> 6;
    const int quad = lane >> 4;
    const int lt   = lane & 15;

    // Phase 1: stage x window f16, copies at even and +1 shift (halves [0,4928))
    for (int e = tid; e < 22 * 112; e += 256) {
        int ch = e / 112, j = e - ch * 112;
        int s = w0 + j;
        float v = (j < 85 && s < SAMPLES) ? x[(b * CHANS + ch) * SAMPLES + s] : 0.0f;
        _Float16 h = (_Float16)v;
        sm16[e] = h;
        if (j > 0) sm16[2464 + e - 1] = h;
        if (j == 111) sm16[2464 + e] = (_Float16)0.0f;
    }
    __syncthreads();

    // Phase 2: depthwise conv as MFMA-f16 GEMM per channel
    {
        half8 afr0[3], afr1[3];
        const _Float16* ktb = (const _Float16*)(cst + WS_KTB);
        #pragma unroll
        for (int kt = 0; kt < 3; ++kt) {
            afr0[kt] = *(const half8*)(ktb + lt * 96 + kt * 32 + quad * 8);
            afr1[kt] = *(const half8*)(ktb + (lt + 16) * 96 + kt * 32 + quad * 8);
        }
        const int xebase = (lt & 1) ? (2464 - 1 + lt) : lt;  // parity-selected copy
        const int* smi = (const int*)sm;

        for (int c = wid; c < CHANS; c += 4) {
            f32x4 acc0 = {0.f, 0.f, 0.f, 0.f}, acc1 = {0.f, 0.f, 0.f, 0.f};
            #pragma unroll
            for (int kt = 0; kt < 3; ++kt) {
                int bi = (xebase + c * 112 + quad * 8 + kt * 32) >> 1;
                union { int i[4]; half8 s; } B;
                B.i[0] = smi[bi];     B.i[1] = smi[bi + 1];
                B.i[2] = smi[bi + 2]; B.i[3] = smi[bi + 3];
                acc0 = __builtin_amdgcn_mfma_f32_16x16x32_f16(afr0[kt], B.s, acc0, 0, 0, 0);
                acc1 = __builtin_amdgcn_mfma_f32_16x16x32_f16(afr1[kt], B.s, acc1, 0, 0, 0);
            }
            const int t = lt;
            if (t < TW) {
                {
                    const v2f* w2v = (const v2f*)(cst + WS_W2T + c * 24 + quad * 4);
                    const v2f* ddv = (const v2f*)(cst + WS_D + quad * 4);
                    v2f g01 = gelu2(__builtin_elementwise_fma(w2v[0], (v2f){acc0[0], acc0[1]}, ddv[0]));
                    v2f g23 = gelu2(__builtin_elementwise_fma(w2v[1], (v2f){acc0[2], acc0[3]}, ddv[1]));
                    union { _Float16 h[4]; uint2 v; } pk;
                    pk.h[0] = (_Float16)g01.x; pk.h[1] = (_Float16)g01.y;
                    pk.h[2] = (_Float16)g23.x; pk.h[3] = (_Float16)g23.y;
                    *(uint2*)&sm16[OG16 + t * 532 + c * 24 + quad * 4] = pk.v;
                }
                if (quad < 2) {
                    const v2f* w2v = (const v2f*)(cst + WS_W2T + c * 24 + 16 + quad * 4);
                    const v2f* ddv = (const v2f*)(cst + WS_D + 16 + quad * 4);
                    v2f g01 = gelu2(__builtin_elementwise_fma(w2v[0], (v2f){acc1[0], acc1[1]}, ddv[0]));
                    v2f g23 = gelu2(__builtin_elementwise_fma(w2v[1], (v2f){acc1[2], acc1[3]}, ddv[1]));
                    union { _Float16 h[4]; uint2 v; } pk;
                    pk.h[0] = (_Float16)g01.x; pk.h[1] = (_Float16)g01.y;
                    pk.h[2] = (_Float16)g23.x; pk.h[3] = (_Float16)g23.y;
                    *(uint2*)&sm16[OG16 + t * 532 + c * 24 + 16 + quad * 4] = pk.v;
                }
            }
        }
    }
    __syncthreads();

    // Phase 3: depth attention: mean over c, (7,1) depth conv, softmax over depth
    for (int e = tid; e < CD1 * TW; e += 256) {
        int d = e / TW, tt = e - d * TW;
        float s = 0.0f;
        #pragma unroll
        for (int ch = 0; ch < CHANS; ++ch) s += (float)sm16[OG16 + tt * 532 + ch * 24 + d];
        sm[XPF + e] = s * (1.0f / 22.0f);
    }
    __syncthreads();
    for (int e = tid; e < CD1 * TW; e += 256) {
        int d = e / TW, tt = e - d * TW;
        float y = dab_g[0];
        #pragma unroll
        for (int j = 0; j < 7; ++j) {
            int dd = d + j - 3;
            if (dd >= 0 && dd < CD1) y += daw_g[j] * sm[XPF + dd * TW + tt];
        }
        sm[OSF + d * 12 + tt] = y;
    }
    __syncthreads();
    if (tid < TW) {
        float mx = -1e30f;
        for (int d = 0; d < CD1; ++d) mx = fmaxf(mx, sm[OSF + d * 12 + tid]);
        float sum = 0.0f;
        for (int d = 0; d < CD1; ++d) {
            float e2 = expf(sm[OSF + d * 12 + tid] - mx);
            sm[OSF + d * 12 + tid] = e2;
            sum += e2;
        }
        float inv = 1.0f / sum;
        for (int d = 0; d < CD1; ++d) sm[OSF + d * 12 + tid] *= inv;
    }
    __syncthreads();

    const int c4 = tid / TW;        // 0..21 (tid<242)
    const int t4 = tid - c4 * TW;   // 0..10
    const bool act = (tid < 242);

    // Zero XA pad cols 22..31 for rows 0..98 (kills stale-LDS in the A*0 path)
    for (int e = tid; e < 990; e += 256) {
        int row = e / 10, d = 22 + (e - row * 10);
        sm16[XA16H + row * 36 + d] = (_Float16)0.0f;
        sm16[XA16L + row * 36 + d] = (_Float16)0.0f;
    }

    // Phase 4: cconv1 (packed-f32 pairs) -> xo registers; write XA hi + lo*4096
    float xo[CD2];
    if (act) {
        float garr[CD1];
        {
            union { uint u[12]; _Float16 h[24]; } gg;
            const uint* gsrc = (const uint*)&sm16[OG16 + t4 * 532 + c4 * 24];
            #pragma unroll
            for (int q = 0; q < 12; ++q) gg.u[q] = gsrc[q];
            #pragma unroll
            for (int i = 0; i < 24; ++i) garr[i] = (float)gg.h[i];
        }
        v2f acc2[4];
        acc2[0] = *(const v2f*)(cst + WS_B3 + 0);
        acc2[1] = *(const v2f*)(cst + WS_B3 + 2);
        acc2[2] = *(const v2f*)(cst + WS_B3 + 4);
        acc2[3] = *(const v2f*)(cst + WS_B3 + 6);
        float acc8 = cst[WS_B3 + 8];
        #pragma unroll
        for (int i = 0; i < CD1; ++i) {
            float s = sm[OSF + i * 12 + t4];
            float p = s * garr[i];
            v2f pv = V2s(p);
            const v2f* wv = (const v2f*)(cst + WS_CC1T + i * 12);
            acc2[0] = __builtin_elementwise_fma(wv[0], pv, acc2[0]);
            acc2[1] = __builtin_elementwise_fma(wv[1], pv, acc2[1]);
            acc2[2] = __builtin_elementwise_fma(wv[2], pv, acc2[2]);
            acc2[3] = __builtin_elementwise_fma(wv[3], pv, acc2[3]);
            acc8 = fmaf(cst[WS_CC1T + i * 12 + 8], p, acc8);
        }
        xo[0] = acc2[0].x; xo[1] = acc2[0].y; xo[2] = acc2[1].x; xo[3] = acc2[1].y;
        xo[4] = acc2[2].x; xo[5] = acc2[2].y; xo[6] = acc2[3].x; xo[7] = acc2[3].y;
        xo[8] = acc8;
        #pragma unroll
        for (int f = 0; f < 9; ++f) {
            float v = xo[f];
            _Float16 hi = (_Float16)v;
            _Float16 lo = (_Float16)((v - (float)hi) * LOSCALE);
            int row = (t4 * 9 + f) * 36 + c4;
            sm16[XA16H + row] = hi;
            sm16[XA16L + row] = lo;
        }
    }
    __syncthreads();

    // Phase 5: 5 Chebyshev layers. GEMM-1 via scaled split-f16 MFMA (f32-grade);
    // contraction (27->9) in packed-f32 VALU with register xo.
    const int Tsel = wid >> 1;
    const int ccG1 = (wid & 1) * 16 + lt;
    const _Float16* t16 = (const _Float16*)(cst + WS_T16);
    const half8 bT_hi = *(const half8*)(t16 + Tsel * 1024 + ccG1 * 32 + quad * 8);
    const half8 bT_lo = *(const half8*)(t16 + 2048 + Tsel * 1024 + ccG1 * 32 + quad * 8);
    const f32x4 zz = {0.f, 0.f, 0.f, 0.f};
    const f32x4 scv = {LOSCALE_I, LOSCALE_I, LOSCALE_I, LOSCALE_I};

    #pragma unroll 1
    for (int l = 0; l < 5; ++l) {
        // GEMM-1: Y = X * T^T; 6 full M-tiles + 1 overlapping tail tile (rows 83..98)
        f32x4 y[7];
        #pragma unroll
        for (int mt = 0; mt < 7; ++mt) {
            const int rowb = (mt < 6) ? mt * 16 : 83;
            half8 ah = ld_half8(&sm16[XA16H + (rowb + lt) * 36 + quad * 8]);
            half8 al = ld_half8(&sm16[XA16L + (rowb + lt) * 36 + quad * 8]);
            f32x4 ahi = __builtin_amdgcn_mfma_f32_16x16x32_f16(ah, bT_hi, zz, 0, 0, 0);
            f32x4 alo = __builtin_amdgcn_mfma_f32_16x16x32_f16(al, bT_hi, zz, 0, 0, 0);
            alo = __builtin_amdgcn_mfma_f32_16x16x32_f16(ah, bT_lo, alo, 0, 0, 0);
            y[mt] = __builtin_elementwise_fma(alo, scv, ahi);
        }
        // scatter Y f32 -> YF[Tsel][f][c*11+t]
        if (ccG1 < 22) {
            const int cb = ccG1 * 11;
            #pragma unroll
            for (int mt = 0; mt < 6; ++mt) {
                int m0 = mt * 16 + quad * 4;       // <= 92: always in range
                int t0 = (m0 * 57) >> 9;
                int f0 = m0 - 9 * t0;
                #pragma unroll
                for (int r = 0; r < 4; ++r) {
                    sm[YF + (Tsel * 9 + f0) * 242 + cb + t0] = y[mt][r];
                    ++f0; if (f0 == 9) { f0 = 0; ++t0; }
                }
            }
            {   // tail tile: m = 83 + quad*4 + r; keep only m=96..98 (t=10, f=6..8)
                int m0 = 83 + quad * 4;
                #pragma unroll
                for (int r = 0; r < 4; ++r) {
                    int m = m0 + r;
                    if (m >= 96)
                        sm[YF + (Tsel * 9 + (m - 90)) * 242 + cb + 10] = y[6][r];
                }
            }
        }
        __syncthreads();

        if (act) {
            const float* blp = cst + WS_BL + l * 9;
            v2f o2_0 = {blp[0], blp[1]}, o2_1 = {blp[2], blp[3]};
            v2f o2_2 = {blp[4], blp[5]}, o2_3 = {blp[6], blp[7]};
            float o8 = blp[8];
            #pragma unroll
            for (int f = 0; f < CD2; ++f) {
                float xv  = xo[f];
                float yv1 = sm[YF + f * 242 + tid];
                float yv2 = sm[YF + (9 + f) * 242 + tid];
                v2f xp = V2s(xv), y1p = V2s(yv1), y2p = V2s(yv2);
                const float* wb = cst + WS_WCB + (l * 9 + f) * 36;
                const v2f* w0 = (const v2f*)(wb);
                const v2f* w1 = (const v2f*)(wb + 12);
                const v2f* w2 = (const v2f*)(wb + 24);
                o2_0 = __builtin_elementwise_fma(w0[0], xp,
                        __builtin_elementwise_fma(w1[0], y1p,
                         __builtin_elementwise_fma(w2[0], y2p, o2_0)));
                o2_1 = __builtin_elementwise_fma(w0[1], xp,
                        __builtin_elementwise_fma(w1[1], y1p,
                         __builtin_elementwise_fma(w2[1], y2p, o2_1)));
                o2_2 = __builtin_elementwise_fma(w0[2], xp,
                        __builtin_elementwise_fma(w1[2], y1p,
                         __builtin_elementwise_fma(w2[2], y2p, o2_2)));
                o2_3 = __builtin_elementwise_fma(w0[3], xp,
                        __builtin_elementwise_fma(w1[3], y1p,
                         __builtin_elementwise_fma(w2[3], y2p, o2_3)));
                o8 = fmaf(wb[8], xv, fmaf(wb[20], yv1, fmaf(wb[32], yv2, o8)));
            }
            o2_0 = __builtin_elementwise_max(o2_0, V2s(0.0f));
            o2_1 = __builtin_elementwise_max(o2_1, V2s(0.0f));
            o2_2 = __builtin_elementwise_max(o2_2, V2s(0.0f));
            o2_3 = __builtin_elementwise_max(o2_3, V2s(0.0f));
            xo[0] = o2_0.x; xo[1] = o2_0.y; xo[2] = o2_1.x; xo[3] = o2_1.y;
            xo[4] = o2_2.x; xo[5] = o2_2.y; xo[6] = o2_3.x; xo[7] = o2_3.y;
            xo[8] = fmaxf(o8, 0.0f);
            if (l < 4) {
                #pragma unroll
                for (int f = 0; f < 9; ++f) {
                    float v = xo[f];
                    _Float16 hi = (_Float16)v;
                    _Float16 lo = (_Float16)((v - (float)hi) * LOSCALE);
                    int row = (t4 * 9 + f) * 36 + c4;
                    sm16[XA16H + row] = hi;
                    sm16[XA16L + row] = lo;
                }
            }
        }
        __syncthreads();
    }

    // final X f32 -> XF (reuse YF region; all YF reads completed at last barrier)
    if (act) {
        #pragma unroll
        for (int f = 0; f < 9; ++f) sm[YF + f * 242 + tid] = xo[f];
    }
    __syncthreads();

    // Phase 6: depthwise channel conv (folded bn4) + gelu -> zbuf
    if (tid < CD2 * TW) {
        int f = tid / TW, tt = tid - f * TW;
        float a = cst[WS_B4 + f];
        #pragma unroll
        for (int ch = 0; ch < CHANS; ++ch)
            a = fmaf(cst[WS_CC2 + f * CHANS + ch], sm[YF + f * 242 + ch * 11 + tt], a);
        float z = gelu_fast(a);
        int w = w0 + tt;
        if (w < W1) zbuf[(b * CD2 + f) * W1 + w] = z;
    }
}

__global__ __launch_bounds__(256) void head_kernel(
    const float* __restrict__ ws, const float* __restrict__ fc1w,
    const float* __restrict__ fc1b, const float* __restrict__ w1,
    const float* __restrict__ b1, const float* __restrict__ w2,
    const float* __restrict__ b2, float* __restrict__ out)
{
    __shared__ float red[5][256];
    __shared__ float l5[5];
    __shared__ float hbuf[64];
    const int tid = threadIdx.x;
    const int b = blockIdx.x;
    const float* zb = ws + WS_Z + b * CD2 * W1;

    float part[5] = {0, 0, 0, 0, 0};
    for (int i = tid; i < FEAT; i += 256) {
        int f = i / WP, t = i - f * WP;
        const float* zp = zb + f * W1 + 5 * t;
        float pooled = 0.2f * (zp[0] + zp[1] + zp[2] + zp[3] + zp[4]);
        #pragma unroll
        for (int j = 0; j < 5; ++j) part[j] = fmaf(pooled, fc1w[i * 5 + j], part[j]);
    }
    #pragma unroll
    for (int j = 0; j < 5; ++j) red[j][tid] = part[j];
    __syncthreads();
    for (int ofs = 128; ofs > 0; ofs >>= 1) {
        if (tid < ofs) {
            #pragma unroll
            for (int j = 0; j < 5; ++j) red[j][tid] += red[j][tid + ofs];
        }
        __syncthreads();
    }
    if (tid < 5) l5[tid] = red[tid][0] + fc1b[tid];
    __syncthreads();
    if (tid < 64) {
        float a = b1[tid];
        #pragma unroll
        for (int j = 0; j < 5; ++j) a = fmaf(l5[j], w1[j * 64 + tid], a);
        hbuf[tid] = (a > 0.0f) ? a : expm1f(a);
    }
    __syncthreads();
    if (tid == 0) {
        float o4[4];
        #pragma unroll
        for (int m = 0; m < 4; ++m) {
            float a = b2[m];
            for (int k = 0; k < 64; ++k) a = fmaf(hbuf[k], w2[k * 4 + m], a);
            o4[m] = a;
        }
        float mx = fmaxf(fmaxf(o4[0], o4[1]), fmaxf(o4[2], o4[3]));
        float s = 0.0f;
        #pragma unroll
        for (int m = 0; m < 4; ++m) { o4[m] = expf(o4[m] - mx); s += o4[m]; }
        float inv = 1.0f / s;
        #pragma unroll
        for (int m = 0; m < 4; ++m) out[b * 4 + m] = o4[m] * inv;
    }
}

extern "C" void kernel_launch(void* const* d_in, const int* in_sizes, int n_in,
                              void* d_out, int out_size, void* d_ws, size_t ws_size,
                              hipStream_t stream)
{
    const float* x    = (const float*)d_in[0];
    const float* cw   = (const float*)d_in[1];
    const float* t1w  = (const float*)d_in[2];
    const float* bn1  = (const float*)d_in[3];
    const float* t2w  = (const float*)d_in[4];
    const float* bn2  = (const float*)d_in[5];
    const float* daw  = (const float*)d_in[6];
    const float* dab  = (const float*)d_in[7];
    const float* cc1w = (const float*)d_in[8];
    const float* bn3  = (const float*)d_in[9];
    const float* A    = (const float*)d_in[10];
    const float* Am   = (const float*)d_in[11];
    const float* cbW  = (const float*)d_in[12];
    const float* cbB  = (const float*)d_in[13];
    const float* cc2w = (const float*)d_in[14];
    const float* bn4  = (const float*)d_in[15];
    const float* fc1w = (const float*)d_in[16];
    const float* fc1b = (const float*)d_in[17];
    const float* w1   = (const float*)d_in[18];
    const float* b1   = (const float*)d_in[19];
    const float* w2   = (const float*)d_in[20];
    const float* b2   = (const float*)d_in[21];
    float* ws  = (float*)d_ws;
    float* out = (float*)d_out;

    hipLaunchKernelGGL(precompute_kernel, dim3(1), dim3(256), 0, stream,
                       cw, t1w, bn1, t2w, bn2, cc1w, bn3, A, Am, cbW, cbB, cc2w, bn4, ws);
    hipLaunchKernelGGL(main_kernel, dim3(NT, B_), dim3(256), 0, stream,
                       x, daw, dab, ws);
    hipLaunchKernelGGL(head_kernel, dim3(B_), dim3(256), 0, stream,
                       ws, fc1w, fc1b, w1, b1, w2, b2, out);
}